// Round 1
// baseline (1193.287 us; speedup 1.0000x reference)
//
#include <hip/hip_runtime.h>

#define PP 20000

// ============================================================================
// VN linear, f32: out[p,o,i] = sum_{c<128} in[p,c,i] * W[c,o]
// Grid (625, 2): 32 whole points (96 j) x 64 outputs per block, 256 threads.
// Thread: 6 j x 4 o.  LDS: As [c][j] stride 96 (48K) + Bs [c][o] (32K) = 80 KB.
// ============================================================================
__global__ __launch_bounds__(256) void vn_gemm(const float* __restrict__ in, const float* __restrict__ Wg,
                                               float* __restrict__ out)
{
    __shared__ __align__(16) float As[128*96];
    __shared__ __align__(16) float Bs[128*64];
    const int tid = threadIdx.x;
    const int og  = tid & 15;          // 4 cols each
    const int jg  = tid >> 4;          // 6 rows each
    const int p0  = blockIdx.x * 32;
    const int o0  = blockIdx.y * 64;

    // stage A: 32 points x 384 f32, layout As[c*96 + pl*3 + i]
    for (int f = tid; f < 3072; f += 256) {
        float4 w = *(const float4*)(in + (size_t)p0*384 + f*4);
        int e = f*4;
        int pl = e/384, rem = e - pl*384;
        float vals[4] = {w.x, w.y, w.z, w.w};
        #pragma unroll
        for (int k=0;k<4;++k){
            int c = (rem+k)/3, i = (rem+k) - c*3;
            As[c*96 + pl*3 + i] = vals[k];
        }
    }
    // stage B: 128 rows x 64 cols
    for (int f = tid; f < 2048; f += 256) {
        int r = f >> 4, seg = f & 15;
        *(float4*)(Bs + r*64 + seg*4) = *(const float4*)(Wg + (size_t)r*128 + o0 + seg*4);
    }
    __syncthreads();

    float acc[6][4];
    #pragma unroll
    for (int r=0;r<6;++r)
        #pragma unroll
        for (int o=0;o<4;++o) acc[r][o]=0.f;

    #pragma unroll 2
    for (int c = 0; c < 128; ++c) {
        float2 a01 = *(const float2*)(As + c*96 + jg*6);
        float2 a23 = *(const float2*)(As + c*96 + jg*6 + 2);
        float2 a45 = *(const float2*)(As + c*96 + jg*6 + 4);
        float4 bv  = *(const float4*)(Bs + c*64 + og*4);
        float a[6] = {a01.x,a01.y,a23.x,a23.y,a45.x,a45.y};
        float bb[4] = {bv.x,bv.y,bv.z,bv.w};
        #pragma unroll
        for (int r=0;r<6;++r)
            #pragma unroll
            for (int o=0;o<4;++o) acc[r][o] += a[r]*bb[o];
    }
    #pragma unroll
    for (int pt=0;pt<2;++pt){
        int p = p0 + jg*2 + pt;
        #pragma unroll
        for (int i=0;i<3;++i){
            size_t base = (size_t)p*384 + i;
            #pragma unroll
            for (int o=0;o<4;++o)
                out[base + (size_t)(o0 + og*4 + o)*3] = acc[pt*3+i][o];
        }
    }
}

// ============================================================================
// Attention scores: one block (128 threads) per point.  Reads q from its own
// d_out row (fully, before any write) + gathered k rows (ws) -> computes
// softmax'd attention weights, stores 128 f32 (att[n*8+h]) into the first 128
// floats of ITS OWN d_out row.  Per-point in-place: race-free.
// R0 change: w1 staged TRANSPOSED (w1t[th][cc], ld=132) so the pos-MLP inner
// loop reads both operands as ds_read_b128 (64 LDS instrs/thread vs 256).
// ============================================================================
__global__ __launch_bounds__(128) void attn_score(
    const float* qf, const float* __restrict__ kf,
    const float* __restrict__ sh, const float* __restrict__ dist, const int* __restrict__ idxp,
    const float* __restrict__ gw1, const float* __restrict__ gb1,
    const float* __restrict__ gw2, const float* __restrict__ gb2,
    float* att)
{
    const int p = blockIdx.x, c = threadIdx.x;
    __shared__ __align__(16) float dot_s[16*132];
    __shared__ __align__(16) float pos_s[16*132];
    __shared__ float sh_s[48];
    __shared__ int   nidx[16];
    __shared__ __align__(16) float w1t[8*132];     // transposed: w1t[h*132 + c]
    __shared__ float w2_s[64], b1_s[8], b2_s[8];
    __shared__ float u2_s[16*8], logit_s[16*8];

    if (c < 16) nidx[c] = idxp[p*16 + c];
    if (c < 48) sh_s[c] = sh[(size_t)p*51 + 3 + c];   // sh[:,1:,:]
    #pragma unroll
    for (int f = c; f < 1024; f += 128){
        int th2 = f >> 7, cc2 = f & 127;
        w1t[th2*132 + cc2] = gw1[cc2*8 + th2];
    }
    if (c < 64) w2_s[c] = gw2[c];
    if (c < 8){ b1_s[c]=gb1[c]; b2_s[c]=gb2[c]; }
    size_t qa = (size_t)p*384 + c*3;
    float qx = qf[qa], qy = qf[qa+1], qz = qf[qa+2];
    __syncthreads();

    for (int n=0;n<16;++n){
        size_t kbase = (size_t)nidx[n]*384 + c*3;
        float kx = kf[kbase], ky = kf[kbase+1], kz = kf[kbase+2];
        dot_s[n*132 + c] = kx*qx + ky*qy + kz*qz;
        pos_s[n*132 + c] = (kx-qx)*sh_s[n*3] + (ky-qy)*sh_s[n*3+1] + (kz-qz)*sh_s[n*3+2];
    }
    __syncthreads();

    // 128 tasks = (n,h): head-dot reduction + pos-MLP layer 1, vectorized b128
    const int tn = c >> 3, th = c & 7;
    const float* drow = dot_s + tn*132 + th*16;
    float4 d0 = *(const float4*)(drow);
    float4 d1 = *(const float4*)(drow + 4);
    float4 d2 = *(const float4*)(drow + 8);
    float4 d3 = *(const float4*)(drow + 12);
    float dsum = (d0.x+d0.y+d0.z+d0.w) + (d1.x+d1.y+d1.z+d1.w)
               + (d2.x+d2.y+d2.z+d2.w) + (d3.x+d3.y+d3.z+d3.w);

    float uj = b1_s[th];
    const float* prow = pos_s + tn*132;
    const float* wrow = w1t  + th*132;
    #pragma unroll 8
    for (int cc=0; cc<128; cc+=4){
        float4 pv = *(const float4*)(prow + cc);
        float4 wv = *(const float4*)(wrow + cc);
        uj = fmaf(pv.x, wv.x, uj);
        uj = fmaf(pv.y, wv.y, uj);
        uj = fmaf(pv.z, wv.z, uj);
        uj = fmaf(pv.w, wv.w, uj);
    }
    u2_s[tn*8+th] = fmaxf(uj, 0.f);
    __syncthreads();

    float l = b2_s[th];
    #pragma unroll
    for (int j=0;j<8;++j) l += u2_s[tn*8+j]*w2_s[j*8+th];
    l += dsum + dist[(size_t)p*128 + tn*8 + th];
    logit_s[tn*8+th] = l * 0.25f;                 // / sqrt(DPH=16)
    __syncthreads();

    // softmax over n per head; write att to own d_out row (q fully read by now)
    if (c < 8){
        float mx = -3.0e38f;
        #pragma unroll
        for (int n=0;n<16;++n) mx = fmaxf(mx, logit_s[n*8+c]);
        float e[16], ssum = 0.f;
        #pragma unroll
        for (int n=0;n<16;++n){ e[n] = __expf(logit_s[n*8+c]-mx); ssum += e[n]; }
        float inv = 1.f/ssum;
        #pragma unroll
        for (int n=0;n<16;++n) att[(size_t)p*384 + n*8 + c] = e[n]*inv;
    }
}

// ============================================================================
// Attention apply: one block (128 threads) per point.  Stages its own row's
// att (128 f32) to LDS, then overwrites its own row with tgt2 = sum_n att*v.
// ============================================================================
__global__ __launch_bounds__(128) void attn_apply(const float* __restrict__ vv,
                                                  const int* __restrict__ idxp,
                                                  float* io)
{
    const int p = blockIdx.x, c = threadIdx.x;
    __shared__ float att_s[128];
    __shared__ int   nidx[16];
    if (c < 16) nidx[c] = idxp[p*16 + c];
    att_s[c] = io[(size_t)p*384 + c];      // att[n*8+h] layout
    __syncthreads();                        // all io-row reads complete

    const int h = c >> 4;
    float ax=0.f, ay=0.f, az=0.f;
    #pragma unroll
    for (int n=0;n<16;++n){
        float wgt = att_s[n*8+h];
        size_t vb = (size_t)nidx[n]*384 + c*3;
        ax += wgt*vv[vb]; ay += wgt*vv[vb+1]; az += wgt*vv[vb+2];
    }
    size_t ob = (size_t)p*384 + c*3;
    io[ob] = ax; io[ob+1] = ay; io[ob+2] = az;
}

// ============================================================================
// Fused FF, f32: h = VNrelu(y@fw1, y@fd1); out = h@fw2.
// 32 chunks of 16 DFF cols.  LDS: As 48K + Bu/Bd/W2s 8K each + Hs 6K = 78 KB.
// ============================================================================
__global__ __launch_bounds__(256) void vn_ff(const float* __restrict__ in,
                                             const float* __restrict__ W1, const float* __restrict__ Wd,
                                             const float* __restrict__ W2, float* __restrict__ out)
{
    __shared__ __align__(16) float As[128*96];
    __shared__ __align__(16) float Bu[128*16];
    __shared__ __align__(16) float Bd[128*16];
    __shared__ __align__(16) float W2s[16*128];
    __shared__ __align__(16) float Hs[16*96];
    const int tid = threadIdx.x;
    const int og  = tid & 15;
    const int jg  = tid >> 4;
    const int p0  = blockIdx.x * 32;

    for (int f = tid; f < 3072; f += 256) {
        float4 w = *(const float4*)(in + (size_t)p0*384 + f*4);
        int e = f*4;
        int pl = e/384, rem = e - pl*384;
        float vals[4] = {w.x, w.y, w.z, w.w};
        #pragma unroll
        for (int k=0;k<4;++k){
            int c = (rem+k)/3, i = (rem+k) - c*3;
            As[c*96 + pl*3 + i] = vals[k];
        }
    }

    float acc2[6][8];
    #pragma unroll
    for (int r=0;r<6;++r)
        #pragma unroll
        for (int o=0;o<8;++o) acc2[r][o]=0.f;

    for (int ch = 0; ch < 32; ++ch) {
        const int col0 = ch*16;
        for (int f = tid; f < 512; f += 256) {          // 128 rows x 4 quads
            int r = f >> 2, seg = f & 3;
            *(float4*)(Bu + r*16 + seg*4) = *(const float4*)(W1 + (size_t)r*512 + col0 + seg*4);
            *(float4*)(Bd + r*16 + seg*4) = *(const float4*)(Wd + (size_t)r*512 + col0 + seg*4);
        }
        for (int f = tid; f < 512; f += 256) {          // 16 rows x 32 quads
            int r = f >> 5, seg = f & 31;
            *(float4*)(W2s + r*128 + seg*4) = *(const float4*)(W2 + (size_t)(col0 + r)*128 + seg*4);
        }
        __syncthreads();

        float au[6], ad[6];
        #pragma unroll
        for (int r=0;r<6;++r){ au[r]=0.f; ad[r]=0.f; }
        #pragma unroll 2
        for (int c = 0; c < 128; ++c) {
            float2 a01 = *(const float2*)(As + c*96 + jg*6);
            float2 a23 = *(const float2*)(As + c*96 + jg*6 + 2);
            float2 a45 = *(const float2*)(As + c*96 + jg*6 + 4);
            float b1 = Bu[c*16 + og];
            float b2 = Bd[c*16 + og];
            float a[6] = {a01.x,a01.y,a23.x,a23.y,a45.x,a45.y};
            #pragma unroll
            for (int r=0;r<6;++r){ au[r] += a[r]*b1; ad[r] += a[r]*b2; }
        }
        // VN-relu per point -> Hs[fcol][j]
        #pragma unroll
        for (int pt=0;pt<2;++pt){
            float ux=au[pt*3+0], uy=au[pt*3+1], uz=au[pt*3+2];
            float dx=ad[pt*3+0], dy=ad[pt*3+1], dz=ad[pt*3+2];
            float dot = ux*dx + uy*dy + uz*dz;
            float ksq = dx*dx + dy*dy + dz*dz;
            if (dot < 0.f){
                float fc = dot/(ksq + 1e-6f);
                ux -= fc*dx; uy -= fc*dy; uz -= fc*dz;
            }
            Hs[og*96 + jg*6 + pt*3    ] = ux;
            Hs[og*96 + jg*6 + pt*3 + 1] = uy;
            Hs[og*96 + jg*6 + pt*3 + 2] = uz;
        }
        __syncthreads();
        // acc2 += h-chunk @ fw2-chunk
        #pragma unroll 2
        for (int cc = 0; cc < 16; ++cc) {
            float2 h01 = *(const float2*)(Hs + cc*96 + jg*6);
            float2 h23 = *(const float2*)(Hs + cc*96 + jg*6 + 2);
            float2 h45 = *(const float2*)(Hs + cc*96 + jg*6 + 4);
            float4 w0 = *(const float4*)(W2s + cc*128 + og*8);
            float4 w1 = *(const float4*)(W2s + cc*128 + og*8 + 4);
            float h[6] = {h01.x,h01.y,h23.x,h23.y,h45.x,h45.y};
            float wb[8] = {w0.x,w0.y,w0.z,w0.w,w1.x,w1.y,w1.z,w1.w};
            #pragma unroll
            for (int r=0;r<6;++r)
                #pragma unroll
                for (int o=0;o<8;++o) acc2[r][o] += h[r]*wb[o];
        }
        __syncthreads();
    }
    #pragma unroll
    for (int pt=0;pt<2;++pt){
        int p = p0 + jg*2 + pt;
        #pragma unroll
        for (int i=0;i<3;++i){
            size_t base = (size_t)p*384 + i;
            #pragma unroll
            for (int o=0;o<8;++o)
                out[base + (size_t)(og*8+o)*3] = acc2[pt*3+i][o];
        }
    }
}

// ============================================================================
// VN layernorm: r = a + b2; stats over 128 channel norms.  Element-wise
// in-place (out aliasing a or b2) is race-free.
// ============================================================================
__global__ __launch_bounds__(256) void vn_ln(const float* __restrict__ a, const float* b2,
                                             const float* __restrict__ gamma, const float* __restrict__ beta,
                                             float* out)
{
    const int tid = threadIdx.x;
    const int pl = tid >> 7, c = tid & 127;
    const int p = blockIdx.x*2 + pl;
    size_t base = (size_t)p*384 + c*3;
    float rx = a[base]   + b2[base];
    float ry = a[base+1] + b2[base+1];
    float rz = a[base+2] + b2[base+2];
    float nc = sqrtf(rx*rx + ry*ry + rz*rz);
    float s1 = nc, s2 = nc*nc;
    for (int off=32; off; off>>=1){ s1 += __shfl_down(s1, off); s2 += __shfl_down(s2, off); }
    __shared__ float pr[4][2];
    if ((tid & 63) == 0){ pr[tid>>6][0] = s1; pr[tid>>6][1] = s2; }
    __syncthreads();
    float S1 = pr[pl*2][0] + pr[pl*2+1][0];
    float S2 = pr[pl*2][1] + pr[pl*2+1][1];
    float mu  = S1*(1.f/128.f);
    float var = S2*(1.f/128.f) - mu*mu;
    float nh = (nc - mu)*rsqrtf(var + 1e-5f)*gamma[c] + beta[c];
    float sc = nh/(nc + 1e-6f);
    out[base] = rx*sc; out[base+1] = ry*sc; out[base+2] = rz*sc;
}

// ============================================================================
extern "C" void kernel_launch(void* const* d_in, const int* in_sizes, int n_in,
                              void* d_out, int out_size, void* d_ws, size_t ws_size,
                              hipStream_t stream)
{
    const float* tgt  = (const float*)d_in[0];
    const float* mem  = (const float*)d_in[1];
    const float* sh   = (const float*)d_in[2];
    const float* dist = (const float*)d_in[3];
    const float* Wq   = (const float*)d_in[4];
    const float* Wk   = (const float*)d_in[5];
    const float* Wv   = (const float*)d_in[6];
    const float* Wo   = (const float*)d_in[7];
    const float* gw1  = (const float*)d_in[8];
    const float* gb1  = (const float*)d_in[9];
    const float* gw2  = (const float*)d_in[10];
    const float* gb2  = (const float*)d_in[11];
    const float* ln1g = (const float*)d_in[12];
    const float* ln1b = (const float*)d_in[13];
    const float* ln2g = (const float*)d_in[14];
    const float* ln2b = (const float*)d_in[15];
    const float* fw1  = (const float*)d_in[16];
    const float* fd1  = (const float*)d_in[17];
    const float* fw2  = (const float*)d_in[18];
    const int*   idx  = (const int*)d_in[19];
    // d_in[20], d_in[21] (cnt1, cnt2) unused by the reference.

    // Workspace: EXACTLY 30,720,000 bytes (the size proven functional in R3).
    // d_out (30.72 MB) doubles as the second buffer with per-point in-place
    // row reuse (race-free; see kernel comments).
    //   1. kb = mem@Wk (f32)            -> ws
    //   2. q  = tgt@Wq (f32)            -> d_out
    //   3. attn_score(q, kb)            -> att into own d_out rows
    //   4. vv = mem@Wv (f32)            -> ws        (kb dead)
    //   5. attn_apply(vv, att)          -> tgt2 into own d_out rows
    //   6. t2w = d_out@Wo (f32)         -> ws        (vv dead)
    //   7. LN1(tgt, t2w)                -> ws (in-place)
    //   8. vn_ff(y)                     -> d_out     (tgt2 dead)
    //   9. LN2(y, ffo)                  -> d_out (in-place)
    float* wsf = (float*)d_ws;
    float* outf = (float*)d_out;

    dim3 g2(625,2);
    vn_gemm<<<g2,256,0,stream>>>(mem, Wk, wsf);
    vn_gemm<<<g2,256,0,stream>>>(tgt, Wq, outf);
    attn_score<<<PP,128,0,stream>>>(outf, wsf, sh, dist, idx, gw1, gb1, gw2, gb2, outf);
    vn_gemm<<<g2,256,0,stream>>>(mem, Wv, wsf);
    attn_apply<<<PP,128,0,stream>>>(wsf, idx, outf);
    vn_gemm<<<g2,256,0,stream>>>(outf, Wo, wsf);
    vn_ln<<<PP/2,256,0,stream>>>(tgt, wsf, ln1g, ln1b, wsf);
    vn_ff<<<625,256,0,stream>>>(wsf, fw1, fd1, fw2, outf);
    vn_ln<<<PP/2,256,0,stream>>>(wsf, outf, ln2g, ln2b, outf);
}

// Round 2
// 721.761 us; speedup vs baseline: 1.6533x; 1.6533x over previous
//
#include <hip/hip_runtime.h>

#define PP 20000

typedef short short8 __attribute__((ext_vector_type(8)));
typedef float floatx4 __attribute__((ext_vector_type(4)));

// ---- bf16 split helpers: x ~= hi + lo, |err| <= 2^-18 |x| --------------------
__device__ __forceinline__ unsigned int bf16_rne_bits(float x){
    unsigned int xb = __float_as_uint(x);
    return (xb + 0x7FFFu + ((xb >> 16) & 1u)) & 0xFFFF0000u;
}
__device__ __forceinline__ void split2(float x, short &h, short &l){
    unsigned int hb = bf16_rne_bits(x);
    h = (short)(hb >> 16);
    float r = x - __uint_as_float(hb);
    l = (short)(bf16_rne_bits(r) >> 16);
}

// ============================================================================
// VN linear, f32: out[p,o,i] = sum_{c<128} in[p,c,i] * W[c,o]
// Grid (625, 2): 32 whole points (96 j) x 64 outputs per block, 256 threads.
// ============================================================================
__global__ __launch_bounds__(256) void vn_gemm(const float* __restrict__ in, const float* __restrict__ Wg,
                                               float* __restrict__ out)
{
    __shared__ __align__(16) float As[128*96];
    __shared__ __align__(16) float Bs[128*64];
    const int tid = threadIdx.x;
    const int og  = tid & 15;          // 4 cols each
    const int jg  = tid >> 4;          // 6 rows each
    const int p0  = blockIdx.x * 32;
    const int o0  = blockIdx.y * 64;

    for (int f = tid; f < 3072; f += 256) {
        float4 w = *(const float4*)(in + (size_t)p0*384 + f*4);
        int e = f*4;
        int pl = e/384, rem = e - pl*384;
        float vals[4] = {w.x, w.y, w.z, w.w};
        #pragma unroll
        for (int k=0;k<4;++k){
            int c = (rem+k)/3, i = (rem+k) - c*3;
            As[c*96 + pl*3 + i] = vals[k];
        }
    }
    for (int f = tid; f < 2048; f += 256) {
        int r = f >> 4, seg = f & 15;
        *(float4*)(Bs + r*64 + seg*4) = *(const float4*)(Wg + (size_t)r*128 + o0 + seg*4);
    }
    __syncthreads();

    float acc[6][4];
    #pragma unroll
    for (int r=0;r<6;++r)
        #pragma unroll
        for (int o=0;o<4;++o) acc[r][o]=0.f;

    #pragma unroll 2
    for (int c = 0; c < 128; ++c) {
        float2 a01 = *(const float2*)(As + c*96 + jg*6);
        float2 a23 = *(const float2*)(As + c*96 + jg*6 + 2);
        float2 a45 = *(const float2*)(As + c*96 + jg*6 + 4);
        float4 bv  = *(const float4*)(Bs + c*64 + og*4);
        float a[6] = {a01.x,a01.y,a23.x,a23.y,a45.x,a45.y};
        float bb[4] = {bv.x,bv.y,bv.z,bv.w};
        #pragma unroll
        for (int r=0;r<6;++r)
            #pragma unroll
            for (int o=0;o<4;++o) acc[r][o] += a[r]*bb[o];
    }
    #pragma unroll
    for (int pt=0;pt<2;++pt){
        int p = p0 + jg*2 + pt;
        #pragma unroll
        for (int i=0;i<3;++i){
            size_t base = (size_t)p*384 + i;
            #pragma unroll
            for (int o=0;o<4;++o)
                out[base + (size_t)(o0 + og*4 + o)*3] = acc[pt*3+i][o];
        }
    }
}

// ============================================================================
// Attention scores (R0-vectorized pos-MLP).  Per-point in-place: race-free.
// ============================================================================
__global__ __launch_bounds__(128) void attn_score(
    const float* qf, const float* __restrict__ kf,
    const float* __restrict__ sh, const float* __restrict__ dist, const int* __restrict__ idxp,
    const float* __restrict__ gw1, const float* __restrict__ gb1,
    const float* __restrict__ gw2, const float* __restrict__ gb2,
    float* att)
{
    const int p = blockIdx.x, c = threadIdx.x;
    __shared__ __align__(16) float dot_s[16*132];
    __shared__ __align__(16) float pos_s[16*132];
    __shared__ float sh_s[48];
    __shared__ int   nidx[16];
    __shared__ __align__(16) float w1t[8*132];     // transposed: w1t[h*132 + c]
    __shared__ float w2_s[64], b1_s[8], b2_s[8];
    __shared__ float u2_s[16*8], logit_s[16*8];

    if (c < 16) nidx[c] = idxp[p*16 + c];
    if (c < 48) sh_s[c] = sh[(size_t)p*51 + 3 + c];   // sh[:,1:,:]
    #pragma unroll
    for (int f = c; f < 1024; f += 128){
        int th2 = f >> 7, cc2 = f & 127;
        w1t[th2*132 + cc2] = gw1[cc2*8 + th2];
    }
    if (c < 64) w2_s[c] = gw2[c];
    if (c < 8){ b1_s[c]=gb1[c]; b2_s[c]=gb2[c]; }
    size_t qa = (size_t)p*384 + c*3;
    float qx = qf[qa], qy = qf[qa+1], qz = qf[qa+2];
    __syncthreads();

    for (int n=0;n<16;++n){
        size_t kbase = (size_t)nidx[n]*384 + c*3;
        float kx = kf[kbase], ky = kf[kbase+1], kz = kf[kbase+2];
        dot_s[n*132 + c] = kx*qx + ky*qy + kz*qz;
        pos_s[n*132 + c] = (kx-qx)*sh_s[n*3] + (ky-qy)*sh_s[n*3+1] + (kz-qz)*sh_s[n*3+2];
    }
    __syncthreads();

    const int tn = c >> 3, th = c & 7;
    const float* drow = dot_s + tn*132 + th*16;
    float4 d0 = *(const float4*)(drow);
    float4 d1 = *(const float4*)(drow + 4);
    float4 d2 = *(const float4*)(drow + 8);
    float4 d3 = *(const float4*)(drow + 12);
    float dsum = (d0.x+d0.y+d0.z+d0.w) + (d1.x+d1.y+d1.z+d1.w)
               + (d2.x+d2.y+d2.z+d2.w) + (d3.x+d3.y+d3.z+d3.w);

    float uj = b1_s[th];
    const float* prow = pos_s + tn*132;
    const float* wrow = w1t  + th*132;
    #pragma unroll 8
    for (int cc=0; cc<128; cc+=4){
        float4 pv = *(const float4*)(prow + cc);
        float4 wv = *(const float4*)(wrow + cc);
        uj = fmaf(pv.x, wv.x, uj);
        uj = fmaf(pv.y, wv.y, uj);
        uj = fmaf(pv.z, wv.z, uj);
        uj = fmaf(pv.w, wv.w, uj);
    }
    u2_s[tn*8+th] = fmaxf(uj, 0.f);
    __syncthreads();

    float l = b2_s[th];
    #pragma unroll
    for (int j=0;j<8;++j) l += u2_s[tn*8+j]*w2_s[j*8+th];
    l += dsum + dist[(size_t)p*128 + tn*8 + th];
    logit_s[tn*8+th] = l * 0.25f;                 // / sqrt(DPH=16)
    __syncthreads();

    if (c < 8){
        float mx = -3.0e38f;
        #pragma unroll
        for (int n=0;n<16;++n) mx = fmaxf(mx, logit_s[n*8+c]);
        float e[16], ssum = 0.f;
        #pragma unroll
        for (int n=0;n<16;++n){ e[n] = __expf(logit_s[n*8+c]-mx); ssum += e[n]; }
        float inv = 1.f/ssum;
        #pragma unroll
        for (int n=0;n<16;++n) att[(size_t)p*384 + n*8 + c] = e[n]*inv;
    }
}

// ============================================================================
// Attention apply: one block (128 threads) per point.
// ============================================================================
__global__ __launch_bounds__(128) void attn_apply(const float* __restrict__ vv,
                                                  const int* __restrict__ idxp,
                                                  float* io)
{
    const int p = blockIdx.x, c = threadIdx.x;
    __shared__ float att_s[128];
    __shared__ int   nidx[16];
    if (c < 16) nidx[c] = idxp[p*16 + c];
    att_s[c] = io[(size_t)p*384 + c];      // att[n*8+h] layout
    __syncthreads();                        // all io-row reads complete

    const int h = c >> 4;
    float ax=0.f, ay=0.f, az=0.f;
    #pragma unroll
    for (int n=0;n<16;++n){
        float wgt = att_s[n*8+h];
        size_t vb = (size_t)nidx[n]*384 + c*3;
        ax += wgt*vv[vb]; ay += wgt*vv[vb+1]; az += wgt*vv[vb+2];
    }
    size_t ob = (size_t)p*384 + c*3;
    io[ob] = ax; io[ob+1] = ay; io[ob+2] = az;
}

// ============================================================================
// Fused FF via MFMA (bf16 hi+lo 3-term split ~= f32 accuracy).
// 16 points/block (grid 1250), 256 thr = 4 waves.  M = 64 rows: each point
// padded to 4 rows (x,y,z,0) so the 16x16x32 C-layout (row=(lane>>4)*4+reg)
// makes VN-relu LANE-LOCAL (lane holds one point's x,y,z,pad for one column).
// Wave w owns Mtile w (rows w*16..w*16+15) through GEMM1 -> relu -> H -> GEMM2:
// H is written and read by the same wave (no cross-wave barrier on Hs).
// K1=128; DFF chunked 16 cols (32 chunks); GEMM2 accumulated every 2 chunks
// (K-step 32).  All fragment reads ds_read_b128, XOR slot-swizzled (<=2-way).
// LDS: Ys 32K + W1/Wd 16K + W2 16K + Hs 8K = 72 KB -> 2 blocks/CU.
// ============================================================================
__global__ __launch_bounds__(256,2) void vn_ff_mfma(const float* __restrict__ in,
    const float* __restrict__ W1, const float* __restrict__ Wd,
    const float* __restrict__ W2, float* __restrict__ out)
{
    __shared__ __align__(16) short Ysh[64*128];
    __shared__ __align__(16) short Ysl[64*128];
    __shared__ __align__(16) short Ws1h[16*128];
    __shared__ __align__(16) short Ws1l[16*128];
    __shared__ __align__(16) short Wsdh[16*128];
    __shared__ __align__(16) short Wsdl[16*128];
    __shared__ __align__(16) short Ws2h[128*32];
    __shared__ __align__(16) short Ws2l[128*32];
    __shared__ __align__(16) short Hsh[64*32];
    __shared__ __align__(16) short Hsl[64*32];

    const int tid  = threadIdx.x;
    const int wv   = tid >> 6;
    const int lane = tid & 63;
    const int mrow = lane & 15;    // A-row within tile == B-col within tile
    const int kgrp = lane >> 4;    // 0..3 (k-group of 8)
    const int p0   = blockIdx.x * 16;

    // ---- stage Y: 16 pts, row = pl*4 + i (i==3 rows zero-padded), col = c --
    for (int f = tid; f < 2048; f += 256){              // zero the 16 pad rows
        int row = (f >> 7)*4 + 3, k = f & 127;
        Ysh[row*128 + k] = 0; Ysl[row*128 + k] = 0;
    }
    #pragma unroll
    for (int t = 0; t < 6; ++t){
        int f = tid + t*256;                            // 1536 float4 total
        float4 w4 = *(const float4*)(in + (size_t)p0*384 + f*4);
        int e = f*4, pl = e/384, rem = e - pl*384;
        float vv4[4] = {w4.x, w4.y, w4.z, w4.w};
        #pragma unroll
        for (int j=0;j<4;++j){
            int c = (rem+j)/3, i = (rem+j) - c*3;
            int row = pl*4 + i;
            int idx = row*128 + (((c>>3) ^ (row&7)) << 3) + (c&7);
            short h, l; split2(vv4[j], h, l);
            Ysh[idx] = h; Ysl[idx] = l;
        }
    }

    floatx4 acc2[8];
    #pragma unroll
    for (int nt=0;nt<8;++nt) acc2[nt] = (floatx4){0.f,0.f,0.f,0.f};

    for (int ch = 0; ch < 32; ++ch){
        __syncthreads();   // prev-chunk B-frag reads done (and Y-stage at ch=0)
        // ---- stage W1/Wd chunk cols [ch*16, ch*16+16), transposed + split --
        {
            const int col0 = ch*16;
            const int n = tid & 15, kg = tid >> 4;      // n: col, kg: k-group
            short8 h1, l1, hd, ld;
            #pragma unroll
            for (int j=0;j<8;++j){
                int k = kg*8 + j;
                float a = W1[(size_t)k*512 + col0 + n];
                float b = Wd[(size_t)k*512 + col0 + n];
                short hh, ll;
                split2(a, hh, ll); h1[j]=hh; l1[j]=ll;
                split2(b, hh, ll); hd[j]=hh; ld[j]=ll;
            }
            int base = n*128 + ((kg ^ (n&7)) << 3);
            *(short8*)(Ws1h+base) = h1; *(short8*)(Ws1l+base) = l1;
            *(short8*)(Wsdh+base) = hd; *(short8*)(Wsdl+base) = ld;
            if ((ch & 1) == 0){                         // stage W2 k-rows for this pair
                const int k0 = (ch >> 1) * 32;
                const int n2 = tid & 127, kg2 = tid >> 7;   // kg2: 0..1
                short8 hw[2], lw[2];
                #pragma unroll
                for (int j=0;j<16;++j){
                    int k = kg2*16 + j;
                    float a = W2[(size_t)(k0+k)*128 + n2];
                    short hh, ll; split2(a, hh, ll);
                    hw[j>>3][j&7] = hh; lw[j>>3][j&7] = ll;
                }
                #pragma unroll
                for (int s=0;s<2;++s){
                    int slot = kg2*2 + s;
                    int b2 = n2*32 + ((slot ^ ((n2>>1)&3)) << 3);
                    *(short8*)(Ws2h+b2) = hw[s];
                    *(short8*)(Ws2l+b2) = lw[s];
                }
            }
        }
        __syncthreads();   // staging visible

        // ---- GEMM1: wave wv computes Mtile wv for both U and D (K=128) ----
        floatx4 aU = {0.f,0.f,0.f,0.f}, aD = {0.f,0.f,0.f,0.f};
        const int arow = wv*16 + mrow;
        #pragma unroll
        for (int ks=0;ks<4;++ks){
            int slot = ks*4 + kgrp;
            int aoff = arow*128 + ((slot ^ (arow&7)) << 3);
            short8 ah = *(const short8*)(Ysh + aoff);
            short8 al = *(const short8*)(Ysl + aoff);
            int boff = mrow*128 + ((slot ^ (mrow&7)) << 3);
            short8 b1h = *(const short8*)(Ws1h + boff);
            short8 b1l = *(const short8*)(Ws1l + boff);
            short8 bdh = *(const short8*)(Wsdh + boff);
            short8 bdl = *(const short8*)(Wsdl + boff);
            aU = __builtin_amdgcn_mfma_f32_16x16x32_bf16(ah, b1h, aU, 0,0,0);
            aU = __builtin_amdgcn_mfma_f32_16x16x32_bf16(ah, b1l, aU, 0,0,0);
            aU = __builtin_amdgcn_mfma_f32_16x16x32_bf16(al, b1h, aU, 0,0,0);
            aD = __builtin_amdgcn_mfma_f32_16x16x32_bf16(ah, bdh, aD, 0,0,0);
            aD = __builtin_amdgcn_mfma_f32_16x16x32_bf16(ah, bdl, aD, 0,0,0);
            aD = __builtin_amdgcn_mfma_f32_16x16x32_bf16(al, bdh, aD, 0,0,0);
        }

        // ---- VN-relu, lane-local (lane = point wv*4+(lane>>4), col ch*16+mrow)
        {
            float ux=aU[0], uy=aU[1], uz=aU[2];
            float dx=aD[0], dy=aD[1], dz=aD[2];
            float dot = ux*dx + uy*dy + uz*dz;
            float ksq = dx*dx + dy*dy + dz*dz;
            if (dot < 0.f){
                float fc = dot/(ksq + 1e-6f);
                ux -= fc*dx; uy -= fc*dy; uz -= fc*dz;
            }
            int col  = (ch & 1)*16 + mrow;              // local DFF col in Hs
            int slot = col >> 3, cl = col & 7;
            float hv[4] = {ux, uy, uz, 0.f};
            #pragma unroll
            for (int r=0;r<4;++r){
                int row = wv*16 + kgrp*4 + r;           // C-row = (lane>>4)*4+r
                int idx = row*32 + ((slot ^ ((row>>1)&3)) << 3) + cl;
                short h, l; split2(hv[r], h, l);
                Hsh[idx] = h; Hsl[idx] = l;
            }
        }

        // ---- GEMM2 every 2 chunks: acc2 += H(64x32) @ W2slice(32x128) ------
        if (ch & 1){
            const int arow2 = wv*16 + mrow;
            int aoff = arow2*32 + ((kgrp ^ ((arow2>>1)&3)) << 3);
            short8 ah = *(const short8*)(Hsh + aoff);
            short8 al = *(const short8*)(Hsl + aoff);
            #pragma unroll
            for (int nt=0;nt<8;++nt){
                int bcol = nt*16 + mrow;
                int boff = bcol*32 + ((kgrp ^ ((bcol>>1)&3)) << 3);
                short8 bh = *(const short8*)(Ws2h + boff);
                short8 bl = *(const short8*)(Ws2l + boff);
                acc2[nt] = __builtin_amdgcn_mfma_f32_16x16x32_bf16(ah, bh, acc2[nt], 0,0,0);
                acc2[nt] = __builtin_amdgcn_mfma_f32_16x16x32_bf16(ah, bl, acc2[nt], 0,0,0);
                acc2[nt] = __builtin_amdgcn_mfma_f32_16x16x32_bf16(al, bh, acc2[nt], 0,0,0);
            }
        }
    }

    // ---- epilogue: C row = wv*16 + (lane>>4)*4 + r -> point wv*4+(lane>>4), i=r
    const int p = p0 + wv*4 + kgrp;
    #pragma unroll
    for (int nt=0;nt<8;++nt){
        int o = nt*16 + mrow;
        size_t base = (size_t)p*384 + (size_t)o*3;
        out[base    ] = acc2[nt][0];
        out[base + 1] = acc2[nt][1];
        out[base + 2] = acc2[nt][2];
    }
}

// ============================================================================
// VN layernorm: r = a + b2; stats over 128 channel norms.
// ============================================================================
__global__ __launch_bounds__(256) void vn_ln(const float* __restrict__ a, const float* b2,
                                             const float* __restrict__ gamma, const float* __restrict__ beta,
                                             float* out)
{
    const int tid = threadIdx.x;
    const int pl = tid >> 7, c = tid & 127;
    const int p = blockIdx.x*2 + pl;
    size_t base = (size_t)p*384 + c*3;
    float rx = a[base]   + b2[base];
    float ry = a[base+1] + b2[base+1];
    float rz = a[base+2] + b2[base+2];
    float nc = sqrtf(rx*rx + ry*ry + rz*rz);
    float s1 = nc, s2 = nc*nc;
    for (int off=32; off; off>>=1){ s1 += __shfl_down(s1, off); s2 += __shfl_down(s2, off); }
    __shared__ float pr[4][2];
    if ((tid & 63) == 0){ pr[tid>>6][0] = s1; pr[tid>>6][1] = s2; }
    __syncthreads();
    float S1 = pr[pl*2][0] + pr[pl*2+1][0];
    float S2 = pr[pl*2][1] + pr[pl*2+1][1];
    float mu  = S1*(1.f/128.f);
    float var = S2*(1.f/128.f) - mu*mu;
    float nh = (nc - mu)*rsqrtf(var + 1e-5f)*gamma[c] + beta[c];
    float sc = nh/(nc + 1e-6f);
    out[base] = rx*sc; out[base+1] = ry*sc; out[base+2] = rz*sc;
}

// ============================================================================
extern "C" void kernel_launch(void* const* d_in, const int* in_sizes, int n_in,
                              void* d_out, int out_size, void* d_ws, size_t ws_size,
                              hipStream_t stream)
{
    const float* tgt  = (const float*)d_in[0];
    const float* mem  = (const float*)d_in[1];
    const float* sh   = (const float*)d_in[2];
    const float* dist = (const float*)d_in[3];
    const float* Wq   = (const float*)d_in[4];
    const float* Wk   = (const float*)d_in[5];
    const float* Wv   = (const float*)d_in[6];
    const float* Wo   = (const float*)d_in[7];
    const float* gw1  = (const float*)d_in[8];
    const float* gb1  = (const float*)d_in[9];
    const float* gw2  = (const float*)d_in[10];
    const float* gb2  = (const float*)d_in[11];
    const float* ln1g = (const float*)d_in[12];
    const float* ln1b = (const float*)d_in[13];
    const float* ln2g = (const float*)d_in[14];
    const float* ln2b = (const float*)d_in[15];
    const float* fw1  = (const float*)d_in[16];
    const float* fd1  = (const float*)d_in[17];
    const float* fw2  = (const float*)d_in[18];
    const int*   idx  = (const int*)d_in[19];

    float* wsf = (float*)d_ws;
    float* outf = (float*)d_out;

    dim3 g2(625,2);
    vn_gemm<<<g2,256,0,stream>>>(mem, Wk, wsf);
    vn_gemm<<<g2,256,0,stream>>>(tgt, Wq, outf);
    attn_score<<<PP,128,0,stream>>>(outf, wsf, sh, dist, idx, gw1, gb1, gw2, gb2, outf);
    vn_gemm<<<g2,256,0,stream>>>(mem, Wv, wsf);
    attn_apply<<<PP,128,0,stream>>>(wsf, idx, outf);
    vn_gemm<<<g2,256,0,stream>>>(outf, Wo, wsf);
    vn_ln<<<PP/2,256,0,stream>>>(tgt, wsf, ln1g, ln1b, wsf);
    vn_ff_mfma<<<1250,256,0,stream>>>(wsf, fw1, fd1, fw2, outf);
    vn_ln<<<PP/2,256,0,stream>>>(wsf, outf, ln2g, ln2b, outf);
}

// Round 3
// 600.828 us; speedup vs baseline: 1.9861x; 1.2013x over previous
//
#include <hip/hip_runtime.h>

#define PP 20000

typedef short short8 __attribute__((ext_vector_type(8)));
typedef float floatx4 __attribute__((ext_vector_type(4)));

// ---- bf16 split helpers: x ~= hi + lo, |err| <= 2^-18 |x| --------------------
__device__ __forceinline__ unsigned int bf16_rne_bits(float x){
    unsigned int xb = __float_as_uint(x);
    return (xb + 0x7FFFu + ((xb >> 16) & 1u)) & 0xFFFF0000u;
}
__device__ __forceinline__ void split2(float x, short &h, short &l){
    unsigned int hb = bf16_rne_bits(x);
    h = (short)(hb >> 16);
    float r = x - __uint_as_float(hb);
    l = (short)(bf16_rne_bits(r) >> 16);
}

// ============================================================================
// VN linear via MFMA (bf16 hi+lo 3-term split, same validated scheme as vn_ff).
// out[p,o,i] = sum_{c<128} in[p,c,i] * W[c,o].
// 16 points/block (grid 1250), 256 thr = 4 waves.  M=64 rows (4/point, padded),
// K=128, N=128 chunked as 4 x 32 cols.  Wave w owns rows w*16..w*16+15.
// K completes inside each chunk -> chunk-local accumulators (no runtime idx).
// LDS: Ys 32K + B 16K = 48 KB -> 3 blocks/CU.
// ============================================================================
__global__ __launch_bounds__(256) void vn_gemm_mfma(const float* __restrict__ in,
    const float* __restrict__ Wg, float* __restrict__ out)
{
    __shared__ __align__(16) short Ysh[64*128];
    __shared__ __align__(16) short Ysl[64*128];
    __shared__ __align__(16) short Bh[32*128];
    __shared__ __align__(16) short Bl[32*128];

    const int tid  = threadIdx.x;
    const int wv   = tid >> 6;
    const int lane = tid & 63;
    const int mrow = lane & 15;    // A-row within tile == B-col within tile
    const int kgrp = lane >> 4;    // 0..3
    const int p0   = blockIdx.x * 16;

    // ---- stage Y: 16 pts, row = pl*4 + i (i==3 rows zero), col = c ---------
    for (int f = tid; f < 2048; f += 256){
        int row = (f >> 7)*4 + 3, k = f & 127;
        Ysh[row*128 + k] = 0; Ysl[row*128 + k] = 0;
    }
    #pragma unroll
    for (int t = 0; t < 6; ++t){
        int f = tid + t*256;
        float4 w4 = *(const float4*)(in + (size_t)p0*384 + f*4);
        int e = f*4, pl = e/384, rem = e - pl*384;
        float vv4[4] = {w4.x, w4.y, w4.z, w4.w};
        #pragma unroll
        for (int j=0;j<4;++j){
            int c = (rem+j)/3, i = (rem+j) - c*3;
            int row = pl*4 + i;
            int idx = row*128 + (((c>>3) ^ (row&7)) << 3) + (c&7);
            short h, l; split2(vv4[j], h, l);
            Ysh[idx] = h; Ysl[idx] = l;
        }
    }

    for (int ch = 0; ch < 4; ++ch){
        __syncthreads();          // prev chunk's B reads done (Y-stage at ch=0)
        // ---- stage B chunk: cols [ch*32, ch*32+32), transposed + split ----
        {
            const int col0 = ch*32;
            const int col = tid & 31, kg = tid >> 5;     // kg 0..7, 16 k each
            short8 hw[2], lw[2];
            #pragma unroll
            for (int j=0;j<16;++j){
                int k = kg*16 + j;
                float a = Wg[(size_t)k*128 + col0 + col];
                short hh, ll; split2(a, hh, ll);
                hw[j>>3][j&7] = hh; lw[j>>3][j&7] = ll;
            }
            #pragma unroll
            for (int s=0;s<2;++s){
                int slot = kg*2 + s;
                int base = col*128 + ((slot ^ (col&7)) << 3);
                *(short8*)(Bh+base) = hw[s];
                *(short8*)(Bl+base) = lw[s];
            }
        }
        __syncthreads();

        // ---- wave wv: rows wv*16..+15, 2 n-tiles of this chunk, K=128 -----
        const int arow = wv*16 + mrow;
        #pragma unroll
        for (int ntl=0; ntl<2; ++ntl){
            floatx4 acc = {0.f,0.f,0.f,0.f};
            const int lcol = ntl*16 + mrow;
            #pragma unroll
            for (int ks=0;ks<4;++ks){
                int slot = ks*4 + kgrp;
                int aoff = arow*128 + ((slot ^ (arow&7)) << 3);
                short8 ah = *(const short8*)(Ysh + aoff);
                short8 al = *(const short8*)(Ysl + aoff);
                int boff = lcol*128 + ((slot ^ (mrow&7)) << 3);
                short8 bh = *(const short8*)(Bh + boff);
                short8 bl = *(const short8*)(Bl + boff);
                acc = __builtin_amdgcn_mfma_f32_16x16x32_bf16(ah, bh, acc, 0,0,0);
                acc = __builtin_amdgcn_mfma_f32_16x16x32_bf16(ah, bl, acc, 0,0,0);
                acc = __builtin_amdgcn_mfma_f32_16x16x32_bf16(al, bh, acc, 0,0,0);
            }
            // C row = wv*16 + kgrp*4 + r -> point p0+wv*4+kgrp, i=r (r<3)
            const int p = p0 + wv*4 + kgrp;
            const int o = ch*32 + ntl*16 + mrow;
            size_t base = (size_t)p*384 + (size_t)o*3;
            out[base    ] = acc[0];
            out[base + 1] = acc[1];
            out[base + 2] = acc[2];
        }
    }
}

// ============================================================================
// Attention scores (R0-vectorized pos-MLP).  Per-point in-place: race-free.
// ============================================================================
__global__ __launch_bounds__(128) void attn_score(
    const float* qf, const float* __restrict__ kf,
    const float* __restrict__ sh, const float* __restrict__ dist, const int* __restrict__ idxp,
    const float* __restrict__ gw1, const float* __restrict__ gb1,
    const float* __restrict__ gw2, const float* __restrict__ gb2,
    float* att)
{
    const int p = blockIdx.x, c = threadIdx.x;
    __shared__ __align__(16) float dot_s[16*132];
    __shared__ __align__(16) float pos_s[16*132];
    __shared__ float sh_s[48];
    __shared__ int   nidx[16];
    __shared__ __align__(16) float w1t[8*132];     // transposed: w1t[h*132 + c]
    __shared__ float w2_s[64], b1_s[8], b2_s[8];
    __shared__ float u2_s[16*8], logit_s[16*8];

    if (c < 16) nidx[c] = idxp[p*16 + c];
    if (c < 48) sh_s[c] = sh[(size_t)p*51 + 3 + c];   // sh[:,1:,:]
    #pragma unroll
    for (int f = c; f < 1024; f += 128){
        int th2 = f >> 7, cc2 = f & 127;
        w1t[th2*132 + cc2] = gw1[cc2*8 + th2];
    }
    if (c < 64) w2_s[c] = gw2[c];
    if (c < 8){ b1_s[c]=gb1[c]; b2_s[c]=gb2[c]; }
    size_t qa = (size_t)p*384 + c*3;
    float qx = qf[qa], qy = qf[qa+1], qz = qf[qa+2];
    __syncthreads();

    for (int n=0;n<16;++n){
        size_t kbase = (size_t)nidx[n]*384 + c*3;
        float kx = kf[kbase], ky = kf[kbase+1], kz = kf[kbase+2];
        dot_s[n*132 + c] = kx*qx + ky*qy + kz*qz;
        pos_s[n*132 + c] = (kx-qx)*sh_s[n*3] + (ky-qy)*sh_s[n*3+1] + (kz-qz)*sh_s[n*3+2];
    }
    __syncthreads();

    const int tn = c >> 3, th = c & 7;
    const float* drow = dot_s + tn*132 + th*16;
    float4 d0 = *(const float4*)(drow);
    float4 d1 = *(const float4*)(drow + 4);
    float4 d2 = *(const float4*)(drow + 8);
    float4 d3 = *(const float4*)(drow + 12);
    float dsum = (d0.x+d0.y+d0.z+d0.w) + (d1.x+d1.y+d1.z+d1.w)
               + (d2.x+d2.y+d2.z+d2.w) + (d3.x+d3.y+d3.z+d3.w);

    float uj = b1_s[th];
    const float* prow = pos_s + tn*132;
    const float* wrow = w1t  + th*132;
    #pragma unroll 8
    for (int cc=0; cc<128; cc+=4){
        float4 pv = *(const float4*)(prow + cc);
        float4 wv = *(const float4*)(wrow + cc);
        uj = fmaf(pv.x, wv.x, uj);
        uj = fmaf(pv.y, wv.y, uj);
        uj = fmaf(pv.z, wv.z, uj);
        uj = fmaf(pv.w, wv.w, uj);
    }
    u2_s[tn*8+th] = fmaxf(uj, 0.f);
    __syncthreads();

    float l = b2_s[th];
    #pragma unroll
    for (int j=0;j<8;++j) l += u2_s[tn*8+j]*w2_s[j*8+th];
    l += dsum + dist[(size_t)p*128 + tn*8 + th];
    logit_s[tn*8+th] = l * 0.25f;                 // / sqrt(DPH=16)
    __syncthreads();

    if (c < 8){
        float mx = -3.0e38f;
        #pragma unroll
        for (int n=0;n<16;++n) mx = fmaxf(mx, logit_s[n*8+c]);
        float e[16], ssum = 0.f;
        #pragma unroll
        for (int n=0;n<16;++n){ e[n] = __expf(logit_s[n*8+c]-mx); ssum += e[n]; }
        float inv = 1.f/ssum;
        #pragma unroll
        for (int n=0;n<16;++n) att[(size_t)p*384 + n*8 + c] = e[n]*inv;
    }
}

// ============================================================================
// Attention apply: one block (128 threads) per point.
// ============================================================================
__global__ __launch_bounds__(128) void attn_apply(const float* __restrict__ vv,
                                                  const int* __restrict__ idxp,
                                                  float* io)
{
    const int p = blockIdx.x, c = threadIdx.x;
    __shared__ float att_s[128];
    __shared__ int   nidx[16];
    if (c < 16) nidx[c] = idxp[p*16 + c];
    att_s[c] = io[(size_t)p*384 + c];      // att[n*8+h] layout
    __syncthreads();                        // all io-row reads complete

    const int h = c >> 4;
    float ax=0.f, ay=0.f, az=0.f;
    #pragma unroll
    for (int n=0;n<16;++n){
        float wgt = att_s[n*8+h];
        size_t vb = (size_t)nidx[n]*384 + c*3;
        ax += wgt*vv[vb]; ay += wgt*vv[vb+1]; az += wgt*vv[vb+2];
    }
    size_t ob = (size_t)p*384 + c*3;
    io[ob] = ax; io[ob+1] = ay; io[ob+2] = az;
}

// ============================================================================
// Fused FF via MFMA (bf16 hi+lo 3-term split ~= f32 accuracy).
// 16 points/block (grid 1250), 256 thr = 4 waves.  M = 64 rows: each point
// padded to 4 rows (x,y,z,0) so the 16x16x32 C-layout (row=(lane>>4)*4+reg)
// makes VN-relu LANE-LOCAL.  Wave w owns Mtile w through GEMM1 -> relu -> H ->
// GEMM2.  K1=128; DFF chunked 16 cols (32 chunks); GEMM2 every 2 chunks.
// LDS: Ys 32K + W1/Wd 16K + W2 16K + Hs 8K = 72 KB -> 2 blocks/CU.
// ============================================================================
__global__ __launch_bounds__(256,2) void vn_ff_mfma(const float* __restrict__ in,
    const float* __restrict__ W1, const float* __restrict__ Wd,
    const float* __restrict__ W2, float* __restrict__ out)
{
    __shared__ __align__(16) short Ysh[64*128];
    __shared__ __align__(16) short Ysl[64*128];
    __shared__ __align__(16) short Ws1h[16*128];
    __shared__ __align__(16) short Ws1l[16*128];
    __shared__ __align__(16) short Wsdh[16*128];
    __shared__ __align__(16) short Wsdl[16*128];
    __shared__ __align__(16) short Ws2h[128*32];
    __shared__ __align__(16) short Ws2l[128*32];
    __shared__ __align__(16) short Hsh[64*32];
    __shared__ __align__(16) short Hsl[64*32];

    const int tid  = threadIdx.x;
    const int wv   = tid >> 6;
    const int lane = tid & 63;
    const int mrow = lane & 15;
    const int kgrp = lane >> 4;
    const int p0   = blockIdx.x * 16;

    for (int f = tid; f < 2048; f += 256){
        int row = (f >> 7)*4 + 3, k = f & 127;
        Ysh[row*128 + k] = 0; Ysl[row*128 + k] = 0;
    }
    #pragma unroll
    for (int t = 0; t < 6; ++t){
        int f = tid + t*256;
        float4 w4 = *(const float4*)(in + (size_t)p0*384 + f*4);
        int e = f*4, pl = e/384, rem = e - pl*384;
        float vv4[4] = {w4.x, w4.y, w4.z, w4.w};
        #pragma unroll
        for (int j=0;j<4;++j){
            int c = (rem+j)/3, i = (rem+j) - c*3;
            int row = pl*4 + i;
            int idx = row*128 + (((c>>3) ^ (row&7)) << 3) + (c&7);
            short h, l; split2(vv4[j], h, l);
            Ysh[idx] = h; Ysl[idx] = l;
        }
    }

    floatx4 acc2[8];
    #pragma unroll
    for (int nt=0;nt<8;++nt) acc2[nt] = (floatx4){0.f,0.f,0.f,0.f};

    for (int ch = 0; ch < 32; ++ch){
        __syncthreads();
        {
            const int col0 = ch*16;
            const int n = tid & 15, kg = tid >> 4;
            short8 h1, l1, hd, ld;
            #pragma unroll
            for (int j=0;j<8;++j){
                int k = kg*8 + j;
                float a = W1[(size_t)k*512 + col0 + n];
                float b = Wd[(size_t)k*512 + col0 + n];
                short hh, ll;
                split2(a, hh, ll); h1[j]=hh; l1[j]=ll;
                split2(b, hh, ll); hd[j]=hh; ld[j]=ll;
            }
            int base = n*128 + ((kg ^ (n&7)) << 3);
            *(short8*)(Ws1h+base) = h1; *(short8*)(Ws1l+base) = l1;
            *(short8*)(Wsdh+base) = hd; *(short8*)(Wsdl+base) = ld;
            if ((ch & 1) == 0){
                const int k0 = (ch >> 1) * 32;
                const int n2 = tid & 127, kg2 = tid >> 7;
                short8 hw[2], lw[2];
                #pragma unroll
                for (int j=0;j<16;++j){
                    int k = kg2*16 + j;
                    float a = W2[(size_t)(k0+k)*128 + n2];
                    short hh, ll; split2(a, hh, ll);
                    hw[j>>3][j&7] = hh; lw[j>>3][j&7] = ll;
                }
                #pragma unroll
                for (int s=0;s<2;++s){
                    int slot = kg2*2 + s;
                    int b2 = n2*32 + ((slot ^ ((n2>>1)&3)) << 3);
                    *(short8*)(Ws2h+b2) = hw[s];
                    *(short8*)(Ws2l+b2) = lw[s];
                }
            }
        }
        __syncthreads();

        floatx4 aU = {0.f,0.f,0.f,0.f}, aD = {0.f,0.f,0.f,0.f};
        const int arow = wv*16 + mrow;
        #pragma unroll
        for (int ks=0;ks<4;++ks){
            int slot = ks*4 + kgrp;
            int aoff = arow*128 + ((slot ^ (arow&7)) << 3);
            short8 ah = *(const short8*)(Ysh + aoff);
            short8 al = *(const short8*)(Ysl + aoff);
            int boff = mrow*128 + ((slot ^ (mrow&7)) << 3);
            short8 b1h = *(const short8*)(Ws1h + boff);
            short8 b1l = *(const short8*)(Ws1l + boff);
            short8 bdh = *(const short8*)(Wsdh + boff);
            short8 bdl = *(const short8*)(Wsdl + boff);
            aU = __builtin_amdgcn_mfma_f32_16x16x32_bf16(ah, b1h, aU, 0,0,0);
            aU = __builtin_amdgcn_mfma_f32_16x16x32_bf16(ah, b1l, aU, 0,0,0);
            aU = __builtin_amdgcn_mfma_f32_16x16x32_bf16(al, b1h, aU, 0,0,0);
            aD = __builtin_amdgcn_mfma_f32_16x16x32_bf16(ah, bdh, aD, 0,0,0);
            aD = __builtin_amdgcn_mfma_f32_16x16x32_bf16(ah, bdl, aD, 0,0,0);
            aD = __builtin_amdgcn_mfma_f32_16x16x32_bf16(al, bdh, aD, 0,0,0);
        }

        {
            float ux=aU[0], uy=aU[1], uz=aU[2];
            float dx=aD[0], dy=aD[1], dz=aD[2];
            float dot = ux*dx + uy*dy + uz*dz;
            float ksq = dx*dx + dy*dy + dz*dz;
            if (dot < 0.f){
                float fc = dot/(ksq + 1e-6f);
                ux -= fc*dx; uy -= fc*dy; uz -= fc*dz;
            }
            int col  = (ch & 1)*16 + mrow;
            int slot = col >> 3, cl = col & 7;
            float hv[4] = {ux, uy, uz, 0.f};
            #pragma unroll
            for (int r=0;r<4;++r){
                int row = wv*16 + kgrp*4 + r;
                int idx = row*32 + ((slot ^ ((row>>1)&3)) << 3) + cl;
                short h, l; split2(hv[r], h, l);
                Hsh[idx] = h; Hsl[idx] = l;
            }
        }

        if (ch & 1){
            const int arow2 = wv*16 + mrow;
            int aoff = arow2*32 + ((kgrp ^ ((arow2>>1)&3)) << 3);
            short8 ah = *(const short8*)(Hsh + aoff);
            short8 al = *(const short8*)(Hsl + aoff);
            #pragma unroll
            for (int nt=0;nt<8;++nt){
                int bcol = nt*16 + mrow;
                int boff = bcol*32 + ((kgrp ^ ((bcol>>1)&3)) << 3);
                short8 bh = *(const short8*)(Ws2h + boff);
                short8 bl = *(const short8*)(Ws2l + boff);
                acc2[nt] = __builtin_amdgcn_mfma_f32_16x16x32_bf16(ah, bh, acc2[nt], 0,0,0);
                acc2[nt] = __builtin_amdgcn_mfma_f32_16x16x32_bf16(ah, bl, acc2[nt], 0,0,0);
                acc2[nt] = __builtin_amdgcn_mfma_f32_16x16x32_bf16(al, bh, acc2[nt], 0,0,0);
            }
        }
    }

    const int p = p0 + wv*4 + kgrp;
    #pragma unroll
    for (int nt=0;nt<8;++nt){
        int o = nt*16 + mrow;
        size_t base = (size_t)p*384 + (size_t)o*3;
        out[base    ] = acc2[nt][0];
        out[base + 1] = acc2[nt][1];
        out[base + 2] = acc2[nt][2];
    }
}

// ============================================================================
// VN layernorm: r = a + b2; stats over 128 channel norms.
// ============================================================================
__global__ __launch_bounds__(256) void vn_ln(const float* __restrict__ a, const float* b2,
                                             const float* __restrict__ gamma, const float* __restrict__ beta,
                                             float* out)
{
    const int tid = threadIdx.x;
    const int pl = tid >> 7, c = tid & 127;
    const int p = blockIdx.x*2 + pl;
    size_t base = (size_t)p*384 + c*3;
    float rx = a[base]   + b2[base];
    float ry = a[base+1] + b2[base+1];
    float rz = a[base+2] + b2[base+2];
    float nc = sqrtf(rx*rx + ry*ry + rz*rz);
    float s1 = nc, s2 = nc*nc;
    for (int off=32; off; off>>=1){ s1 += __shfl_down(s1, off); s2 += __shfl_down(s2, off); }
    __shared__ float pr[4][2];
    if ((tid & 63) == 0){ pr[tid>>6][0] = s1; pr[tid>>6][1] = s2; }
    __syncthreads();
    float S1 = pr[pl*2][0] + pr[pl*2+1][0];
    float S2 = pr[pl*2][1] + pr[pl*2+1][1];
    float mu  = S1*(1.f/128.f);
    float var = S2*(1.f/128.f) - mu*mu;
    float nh = (nc - mu)*rsqrtf(var + 1e-5f)*gamma[c] + beta[c];
    float sc = nh/(nc + 1e-6f);
    out[base] = rx*sc; out[base+1] = ry*sc; out[base+2] = rz*sc;
}

// ============================================================================
extern "C" void kernel_launch(void* const* d_in, const int* in_sizes, int n_in,
                              void* d_out, int out_size, void* d_ws, size_t ws_size,
                              hipStream_t stream)
{
    const float* tgt  = (const float*)d_in[0];
    const float* mem  = (const float*)d_in[1];
    const float* sh   = (const float*)d_in[2];
    const float* dist = (const float*)d_in[3];
    const float* Wq   = (const float*)d_in[4];
    const float* Wk   = (const float*)d_in[5];
    const float* Wv   = (const float*)d_in[6];
    const float* Wo   = (const float*)d_in[7];
    const float* gw1  = (const float*)d_in[8];
    const float* gb1  = (const float*)d_in[9];
    const float* gw2  = (const float*)d_in[10];
    const float* gb2  = (const float*)d_in[11];
    const float* ln1g = (const float*)d_in[12];
    const float* ln1b = (const float*)d_in[13];
    const float* ln2g = (const float*)d_in[14];
    const float* ln2b = (const float*)d_in[15];
    const float* fw1  = (const float*)d_in[16];
    const float* fd1  = (const float*)d_in[17];
    const float* fw2  = (const float*)d_in[18];
    const int*   idx  = (const int*)d_in[19];

    float* wsf = (float*)d_ws;
    float* outf = (float*)d_out;

    vn_gemm_mfma<<<1250,256,0,stream>>>(mem, Wk, wsf);
    vn_gemm_mfma<<<1250,256,0,stream>>>(tgt, Wq, outf);
    attn_score<<<PP,128,0,stream>>>(outf, wsf, sh, dist, idx, gw1, gb1, gw2, gb2, outf);
    vn_gemm_mfma<<<1250,256,0,stream>>>(mem, Wv, wsf);
    attn_apply<<<PP,128,0,stream>>>(wsf, idx, outf);
    vn_gemm_mfma<<<1250,256,0,stream>>>(outf, Wo, wsf);
    vn_ln<<<PP/2,256,0,stream>>>(tgt, wsf, ln1g, ln1b, wsf);
    vn_ff_mfma<<<1250,256,0,stream>>>(wsf, fw1, fd1, fw2, outf);
    vn_ln<<<PP/2,256,0,stream>>>(wsf, outf, ln2g, ln2b, outf);
}